// Round 6
// baseline (5892.572 us; speedup 1.0000x reference)
//
#include <hip/hip_runtime.h>
#include <cstdint>

typedef unsigned long long u64;

static constexpr int BB = 2;
static constexpr int NN = 16384;
static constexpr int SS = 4096;

// one step of a u64 max-combine via DPP (CTRL is a DPP control immediate)
template <int CTRL>
__device__ __forceinline__ u64 dpp_max_step(u64 k) {
  int lo = (int)(unsigned)(k & 0xffffffffull);
  int hi = (int)(unsigned)(k >> 32);
  int slo = __builtin_amdgcn_update_dpp(0, lo, CTRL, 0xF, 0xF, true);
  int shi = __builtin_amdgcn_update_dpp(0, hi, CTRL, 0xF, 0xF, true);
  u64 o = ((u64)(unsigned)shi << 32) | (u64)(unsigned)slo;
  return (o > k) ? o : k;
}

// spread 4 bits: bit k -> bit 3k (for 12-bit Morton)
__device__ __forceinline__ unsigned spread4(unsigned v) {
  return (v & 1u) | ((v & 2u) << 2) | ((v & 4u) << 4) | ((v & 8u) << 6);
}

__device__ __forceinline__ unsigned cell_of(float x, float y, float z) {
  int cx = (int)floorf((x + 4.f) * 2.f);
  int cy = (int)floorf((y + 4.f) * 2.f);
  int cz = (int)floorf((z + 4.f) * 2.f);
  cx = min(max(cx, 0), 15); cy = min(max(cy, 0), 15); cz = min(max(cz, 0), 15);
  return spread4((unsigned)cx) | (spread4((unsigned)cy) << 1) |
         (spread4((unsigned)cz) << 2);
}

// ---------------------------------------------------------------------------
// Counting sort by 12-bit Morton cell -> float4 {x,y,z,bits(orig_idx)}.
// Within-cell order is atomic-nondeterministic but the FPS output is
// invariant to it (keys carry original indices; skips are provable no-ops).
// ---------------------------------------------------------------------------
__global__ __launch_bounds__(1024) void sort_kernel(
    const float* __restrict__ xyz, float4* __restrict__ spts)
{
  const int b = blockIdx.x;
  const float* X = xyz + (size_t)b * NN * 3;
  float4* SP = spts + (size_t)b * NN;
  const int t = threadIdx.x;
  const int lane = t & 63, wid = t >> 6;

  __shared__ unsigned h[4096];
  __shared__ unsigned wtot[16];
  for (int j = t; j < 4096; j += 1024) h[j] = 0;
  __syncthreads();

  for (int i = 0; i < 16; ++i) {
    int p = i * 1024 + t;
    atomicAdd(&h[cell_of(X[p * 3 + 0], X[p * 3 + 1], X[p * 3 + 2])], 1u);
  }
  __syncthreads();

  unsigned a0 = h[4 * t], a1 = h[4 * t + 1], a2 = h[4 * t + 2], a3 = h[4 * t + 3];
  unsigned s4 = a0 + a1 + a2 + a3;
  unsigned incl = s4;
  for (int off = 1; off < 64; off <<= 1) {
    unsigned v = (unsigned)__shfl_up((int)incl, off);
    if (lane >= off) incl += v;
  }
  if (lane == 63) wtot[wid] = incl;
  __syncthreads();
  if (t == 0) {
    unsigned run = 0;
    for (int j = 0; j < 16; ++j) { unsigned tm = wtot[j]; wtot[j] = run; run += tm; }
  }
  __syncthreads();
  unsigned ex = wtot[wid] + (incl - s4);
  h[4 * t] = ex; h[4 * t + 1] = ex + a0;
  h[4 * t + 2] = ex + a0 + a1; h[4 * t + 3] = ex + a0 + a1 + a2;
  __syncthreads();

  for (int i = 0; i < 16; ++i) {
    int p = i * 1024 + t;
    float x = X[p * 3 + 0], y = X[p * 3 + 1], z = X[p * 3 + 2];
    unsigned pos = atomicAdd(&h[cell_of(x, y, z)], 1u);
    SP[pos] = make_float4(x, y, z, __int_as_float(p));
  }
}

// ---------------------------------------------------------------------------
// FPS with 256-point-granularity exact pruning. One block/batch, 16 waves.
// Wave w owns sorted points [w*1024, w*1024+1023]; slot s of lane L is point
// w*1024 + s*64 + L, so sub j (slots 4j..4j+3) is a CONTIGUOUS 256-point run
// with a tight bbox. Per iteration each lane tests its group's (lane&3) sub
// bbox against that sub's cached exact max key; one ballot yields a 4-bit
// active mask -> up to 4 wave-uniform guarded updates. Skipped subs are
// provably no-ops under both our and the reference's rounding (margin
// 1-2^-16). Keys (dist_bits<<32)|~orig_idx give numpy-exact argmax with
// first-original-index tie-break, invariant to sort nondeterminism.
// Coords are re-loaded from the L2-hot sorted array only on active subs;
// only dists (16) + lane-bbox (6) + group key (2) stay register-resident.
// ---------------------------------------------------------------------------
__global__ __launch_bounds__(1024) void fps_kernel(
    const float* __restrict__ xyz, const float4* __restrict__ spts,
    float* __restrict__ new_xyz)
{
  const int b = blockIdx.x;
  const float* X = xyz + (size_t)b * NN * 3;
  float* NX = new_xyz + (size_t)b * SS * 3;
  const float4* SP = spts + (size_t)b * NN;
  const int t = threadIdx.x;
  const int lane = t & 63, wid = t >> 6;
  const int g = lane & 3;
  const float4* WP = SP + wid * 1024;

  // per-sub bboxes; lane keeps the bbox of its group g
  float bnx = 0.f, bny = 0.f, bnz = 0.f, bxx = 0.f, bxy = 0.f, bxz = 0.f;
#pragma unroll
  for (int j = 0; j < 4; ++j) {
    float mnx = 1e30f, mny = 1e30f, mnz = 1e30f;
    float mxx = -1e30f, mxy = -1e30f, mxz = -1e30f;
#pragma unroll
    for (int s = 0; s < 4; ++s) {
      float4 p = WP[(4 * j + s) * 64 + lane];
      mnx = fminf(mnx, p.x); mxx = fmaxf(mxx, p.x);
      mny = fminf(mny, p.y); mxy = fmaxf(mxy, p.y);
      mnz = fminf(mnz, p.z); mxz = fmaxf(mxz, p.z);
    }
#pragma unroll
    for (int off = 1; off < 64; off <<= 1) {
      mnx = fminf(mnx, __shfl_xor(mnx, off)); mxx = fmaxf(mxx, __shfl_xor(mxx, off));
      mny = fminf(mny, __shfl_xor(mny, off)); mxy = fmaxf(mxy, __shfl_xor(mxy, off));
      mnz = fminf(mnz, __shfl_xor(mnz, off)); mxz = fmaxf(mxz, __shfl_xor(mxz, off));
    }
    if (g == j) { bnx = mnx; bny = mny; bnz = mnz; bxx = mxx; bxy = mxy; bxz = mxz; }
  }

  float d0 = 1e10f, d1 = 1e10f, d2 = 1e10f, d3 = 1e10f,
        d4 = 1e10f, d5 = 1e10f, d6 = 1e10f, d7 = 1e10f,
        d8 = 1e10f, d9 = 1e10f, d10 = 1e10f, d11 = 1e10f,
        d12 = 1e10f, d13 = 1e10f, d14 = 1e10f, d15 = 1e10f;

  // cached exact key of this lane's group; init forces all-active at iter 1
  unsigned klo = 0u, khi = __float_as_uint(1e10f);

  __shared__ u64 s_part[2][16];
  int sel = 0;

  for (int it = 1; it < SS; ++it) {
    const float qx = X[sel * 3 + 0];
    const float qy = X[sel * 3 + 1];
    const float qz = X[sel * 3 + 2];
    if (t == 0) {
      NX[(it - 1) * 3 + 0] = qx;
      NX[(it - 1) * 3 + 1] = qy;
      NX[(it - 1) * 3 + 2] = qz;
    }

    // conservative lower bound of dist^2(q, my group's bbox)
    float tx = fmaxf(fmaxf(__fsub_rn(bnx, qx), __fsub_rn(qx, bxx)), 0.f);
    float ty = fmaxf(fmaxf(__fsub_rn(bny, qy), __fsub_rn(qy, bxy)), 0.f);
    float tz = fmaxf(fmaxf(__fsub_rn(bnz, qz), __fsub_rn(qz, bxz)), 0.f);
    float lb2 = fmaf(tx, tx, fmaf(ty, ty, __fmul_rn(tz, tz)));
    u64 bm = __ballot(__fmul_rn(lb2, 0.99998474f) < __uint_as_float(khi));
    unsigned m = (unsigned)bm & 0xFu;  // lanes 0..3 = groups 0..3 (uniform)

#define UPD1(dd, P)                                                           \
    {                                                                         \
      float dx = __fsub_rn((P).x, qx);                                        \
      float dy = __fsub_rn((P).y, qy);                                        \
      float dz = __fsub_rn((P).z, qz);                                        \
      float dsq = __fadd_rn(__fadd_rn(__fmul_rn(dx, dx), __fmul_rn(dy, dy)),  \
                            __fmul_rn(dz, dz));                               \
      dd = fminf(dd, dsq);                                                    \
      u64 kp = ((u64)__float_as_uint(dd) << 32) |                             \
               (u64)(~__float_as_uint((P).w));                                \
      if (kp > kb) kb = kp;                                                   \
    }
#define SUBUPD(J, DA, DB, DC, DD)                                             \
    if (m & (1u << J)) {                                                      \
      float4 p0 = WP[(4 * J + 0) * 64 + lane];                                \
      float4 p1 = WP[(4 * J + 1) * 64 + lane];                                \
      float4 p2 = WP[(4 * J + 2) * 64 + lane];                                \
      float4 p3 = WP[(4 * J + 3) * 64 + lane];                                \
      u64 kb = 0;                                                             \
      UPD1(DA, p0) UPD1(DB, p1) UPD1(DC, p2) UPD1(DD, p3)                     \
      kb = dpp_max_step<0x111>(kb);                                           \
      kb = dpp_max_step<0x112>(kb);                                           \
      kb = dpp_max_step<0x114>(kb);                                           \
      kb = dpp_max_step<0x118>(kb);                                           \
      kb = dpp_max_step<0x142>(kb);                                           \
      kb = dpp_max_step<0x143>(kb);                                           \
      unsigned nlo = (unsigned)__shfl((int)(unsigned)(kb & 0xffffffffull), 63);\
      unsigned nhi = (unsigned)__shfl((int)(unsigned)(kb >> 32), 63);         \
      if (g == J) { klo = nlo; khi = nhi; }                                   \
    }
    SUBUPD(0, d0,  d1,  d2,  d3)
    SUBUPD(1, d4,  d5,  d6,  d7)
    SUBUPD(2, d8,  d9,  d10, d11)
    SUBUPD(3, d12, d13, d14, d15)
#undef SUBUPD
#undef UPD1

    // wave key = max over the 4 group keys (lane-distributed in quads)
    u64 kw = ((u64)khi << 32) | (u64)klo;
    kw = dpp_max_step<0xB1>(kw);  // quad_perm [1,0,3,2]
    kw = dpp_max_step<0x4E>(kw);  // quad_perm [2,3,0,1]

    const int pb = it & 1;
    if (lane == 63) s_part[pb][wid] = kw;
    __syncthreads();
    u64 kk = s_part[pb][lane & 15];
    kk = dpp_max_step<0x128>(kk);  // row_ror:8
    kk = dpp_max_step<0x124>(kk);  // row_ror:4
    kk = dpp_max_step<0x122>(kk);  // row_ror:2
    kk = dpp_max_step<0x121>(kk);  // row_ror:1
    sel = (int)(~(unsigned)(kk & 0xffffffffull));
    sel = __builtin_amdgcn_readfirstlane(sel);
  }
  if (t == 0) {
    NX[(SS - 1) * 3 + 0] = X[sel * 3 + 0];
    NX[(SS - 1) * 3 + 1] = X[sel * 3 + 1];
    NX[(SS - 1) * 3 + 2] = X[sel * 3 + 2];
  }
}

// ---------------------------------------------------------------------------
// Ball query: one 64-lane wave per query point. Emits the first NS in-radius
// point indices in ascending order (matches reference top_k(-keys) trick),
// pads with the first hit.
// ---------------------------------------------------------------------------
template <int NS>
__global__ __launch_bounds__(256) void ballq_kernel(
    const float* __restrict__ xyz, const float* __restrict__ new_xyz,
    int* __restrict__ out, float r2)
{
  const int q = blockIdx.x * 4 + (threadIdx.x >> 6);
  const int lane = threadIdx.x & 63;
  const int b = q >> 12;  // q / SS
  const float* X = xyz + (size_t)b * NN * 3;
  const float cx = new_xyz[q * 3 + 0];
  const float cy = new_xyz[q * 3 + 1];
  const float cz = new_xyz[q * 3 + 2];
  int* o = out + (size_t)q * NS;
  int base = 0;
  int firstIdx = 0x7fffffff;
  for (int c0 = 0; c0 < NN; c0 += 64) {
    const int p = c0 + lane;
    float dx = __fsub_rn(cx, X[p * 3 + 0]);
    float dy = __fsub_rn(cy, X[p * 3 + 1]);
    float dz = __fsub_rn(cz, X[p * 3 + 2]);
    float d2 = __fadd_rn(__fadd_rn(__fmul_rn(dx, dx), __fmul_rn(dy, dy)),
                         __fmul_rn(dz, dz));
    const bool inb = d2 < r2;
    const unsigned long long mm = __ballot(inb);
    if (inb) {
      int rank = base + (int)__popcll(mm & ((1ull << lane) - 1ull));
      if (rank < NS) {
        o[rank] = p;
        if (rank == 0) firstIdx = p;
      }
    }
    base += (int)__popcll(mm);
    if (base >= NS) break;
  }
#pragma unroll
  for (int off = 32; off >= 1; off >>= 1)
    firstIdx = min(firstIdx, __shfl_xor(firstIdx, off));
  for (int r = base + lane; r < NS; r += 64) o[r] = firstIdx;
}

// ---------------------------------------------------------------------------
// Grouping + 3-layer MLP + max over samples. One thread per (query, sample).
// ---------------------------------------------------------------------------
template <int NS, int C1, int C2, int C3>
__global__ __launch_bounds__(256) void group_mlp_kernel(
    const float* __restrict__ xyz, const float* __restrict__ feat,
    const float* __restrict__ new_xyz, const int* __restrict__ idx,
    const float* __restrict__ w0, const float* __restrict__ b0,
    const float* __restrict__ w1, const float* __restrict__ b1,
    const float* __restrict__ w2, const float* __restrict__ b2,
    float* __restrict__ pf, int chOff)
{
  constexpr int QPB = 256 / NS;
  const int q = blockIdx.x * QPB + (int)(threadIdx.x / NS);
  const int k = (int)(threadIdx.x % NS);
  const int b = q >> 12;
  const int s = q & (SS - 1);
  const float* X = xyz + (size_t)b * NN * 3;
  const float* F = feat + (size_t)b * 6 * NN;
  const int p = idx[(size_t)q * NS + k];

  float in[9];
  in[0] = X[p * 3 + 0] - new_xyz[q * 3 + 0];
  in[1] = X[p * 3 + 1] - new_xyz[q * 3 + 1];
  in[2] = X[p * 3 + 2] - new_xyz[q * 3 + 2];
#pragma unroll
  for (int c = 0; c < 6; ++c) in[3 + c] = F[c * NN + p];

  float h1[C1];
#pragma unroll
  for (int oc = 0; oc < C1; ++oc) {
    float a = b0[oc];
#pragma unroll
    for (int c = 0; c < 9; ++c) a = fmaf(w0[oc * 9 + c], in[c], a);
    h1[oc] = fmaxf(a, 0.f);
  }
  float h2[C2];
#pragma unroll
  for (int oc = 0; oc < C2; ++oc) {
    float a = b1[oc];
#pragma unroll
    for (int c = 0; c < C1; ++c) a = fmaf(w1[oc * C1 + c], h1[c], a);
    h2[oc] = fmaxf(a, 0.f);
  }
#pragma unroll
  for (int oc = 0; oc < C3; ++oc) {
    float a = b2[oc];
#pragma unroll
    for (int c = 0; c < C2; ++c) a = fmaf(w2[oc * C2 + c], h2[c], a);
    float v = fmaxf(a, 0.f);
#pragma unroll
    for (int off = NS / 2; off >= 1; off >>= 1)
      v = fmaxf(v, __shfl_xor(v, off));
    if (k == 0) pf[(((size_t)b * 96) + chOff + oc) * SS + s] = v;
  }
}

// ---------------------------------------------------------------------------
// Image branch + attention + fusion, 32-column LDS tiles.
// ---------------------------------------------------------------------------
__global__ __launch_bounds__(256) void img_fuse_kernel(
    const float* __restrict__ imgf, const float* __restrict__ pf,
    const float* __restrict__ w_img, const float* __restrict__ b_img,
    const float* __restrict__ w_fc2, const float* __restrict__ b_fc2,
    const float* __restrict__ w_fc3, const float* __restrict__ b_fc3,
    const float* __restrict__ w_pc, const float* __restrict__ b_pc,
    const float* __restrict__ w_fuse, const float* __restrict__ b_fuse,
    float* __restrict__ out)
{
  constexpr int TS = 32;
  __shared__ float x_lds[64][TS];
  __shared__ float img_lds[96][TS];
  __shared__ float ri_lds[24][TS];
  __shared__ float att_lds[TS];
  __shared__ float imgn_lds[96][TS];
  __shared__ float pf_lds[96][TS];

  const int blk = blockIdx.x;            // B * (SS/TS) = 256 blocks
  const int b = blk / (SS / TS);
  const int s0 = (blk % (SS / TS)) * TS;
  const int tid = threadIdx.x;

  for (int i = tid; i < 64 * TS; i += 256) {
    int c = i / TS, s = i % TS;
    x_lds[c][s] = imgf[((size_t)b * 64 + c) * SS + s0 + s];
  }
  for (int i = tid; i < 96 * TS; i += 256) {
    int c = i / TS, s = i % TS;
    pf_lds[c][s] = pf[((size_t)b * 96 + c) * SS + s0 + s];
  }
  __syncthreads();

  for (int i = tid; i < 96 * TS; i += 256) {
    int oc = i / TS, s = i % TS;
    float a = b_img[oc];
#pragma unroll
    for (int c = 0; c < 64; ++c) a = fmaf(w_img[oc * 64 + c], x_lds[c][s], a);
    img_lds[oc][s] = fmaxf(a, 0.f);
  }
  __syncthreads();

  for (int i = tid; i < 24 * TS; i += 256) {
    int r = i / TS, s = i % TS;
    float a = b_fc2[r];
#pragma unroll
    for (int c = 0; c < 96; ++c) a = fmaf(w_fc2[r * 96 + c], img_lds[c][s], a);
    ri_lds[r][s] = tanhf(a);
  }
  __syncthreads();

  if (tid < TS) {
    float a = b_fc3[0];
#pragma unroll
    for (int r = 0; r < 24; ++r) a = fmaf(w_fc3[r], ri_lds[r][tid], a);
    att_lds[tid] = 1.f / (1.f + expf(-a));
  }
  __syncthreads();

  for (int i = tid; i < 96 * TS; i += 256) {
    int c = i / TS, s = i % TS;
    float v = img_lds[c][s];
    img_lds[c][s] = fmaf(v, att_lds[s], v);
  }
  __syncthreads();

  for (int i = tid; i < 96 * TS; i += 256) {
    int oc = i / TS, s = i % TS;
    float a = b_pc[oc];
#pragma unroll
    for (int c = 0; c < 96; ++c) a = fmaf(w_pc[oc * 96 + c], img_lds[c][s], a);
    imgn_lds[oc][s] = fmaxf(a, 0.f);
  }
  __syncthreads();

  for (int i = tid; i < 128 * TS; i += 256) {
    int oc = i / TS, s = i % TS;
    float a = b_fuse[oc];
#pragma unroll
    for (int c = 0; c < 96; ++c) a = fmaf(w_fuse[oc * 192 + c], pf_lds[c][s], a);
#pragma unroll
    for (int c = 0; c < 96; ++c) a = fmaf(w_fuse[oc * 192 + 96 + c], imgn_lds[c][s], a);
    out[((size_t)b * 128 + oc) * SS + s0 + s] = fmaxf(a, 0.f);
  }
}

// ---------------------------------------------------------------------------
extern "C" void kernel_launch(void* const* d_in, const int* in_sizes, int n_in,
                              void* d_out, int out_size, void* d_ws, size_t ws_size,
                              hipStream_t stream)
{
  const float* xyz    = (const float*)d_in[0];
  const float* feat   = (const float*)d_in[1];
  const float* imgf   = (const float*)d_in[2];
  const float* w0_0   = (const float*)d_in[3];
  const float* b0_0   = (const float*)d_in[4];
  const float* w0_1   = (const float*)d_in[5];
  const float* b0_1   = (const float*)d_in[6];
  const float* w0_2   = (const float*)d_in[7];
  const float* b0_2   = (const float*)d_in[8];
  const float* w1_0   = (const float*)d_in[9];
  const float* b1_0   = (const float*)d_in[10];
  const float* w1_1   = (const float*)d_in[11];
  const float* b1_1   = (const float*)d_in[12];
  const float* w1_2   = (const float*)d_in[13];
  const float* b1_2   = (const float*)d_in[14];
  const float* w_img  = (const float*)d_in[15];
  const float* b_img  = (const float*)d_in[16];
  const float* w_fc2  = (const float*)d_in[17];
  const float* b_fc2  = (const float*)d_in[18];
  const float* w_fc3  = (const float*)d_in[19];
  const float* b_fc3  = (const float*)d_in[20];
  const float* w_pc   = (const float*)d_in[21];
  const float* b_pc   = (const float*)d_in[22];
  const float* w_fuse = (const float*)d_in[23];
  const float* b_fuse = (const float*)d_in[24];
  float* out = (float*)d_out;

  float4* spts = (float4*)d_ws;                          // B*N float4
  float*  nxyz = (float*)(spts + (size_t)BB * NN);       // B*S*3 f32
  int*    idx0 = (int*)(nxyz + (size_t)BB * SS * 3);     // B*S*16 i32
  int*    idx1 = idx0 + (size_t)BB * SS * 16;            // B*S*32 i32
  float*  pf   = (float*)(idx1 + (size_t)BB * SS * 32);  // B*96*S f32

  sort_kernel<<<BB, 1024, 0, stream>>>(xyz, spts);
  fps_kernel<<<BB, 1024, 0, stream>>>(xyz, spts, nxyz);
  ballq_kernel<16><<<BB * SS / 4, 256, 0, stream>>>(xyz, nxyz, idx0, 0.25f);
  ballq_kernel<32><<<BB * SS / 4, 256, 0, stream>>>(xyz, nxyz, idx1, 1.0f);
  group_mlp_kernel<16, 16, 16, 32><<<BB * SS / 16, 256, 0, stream>>>(
      xyz, feat, nxyz, idx0, w0_0, b0_0, w0_1, b0_1, w0_2, b0_2, pf, 0);
  group_mlp_kernel<32, 32, 32, 64><<<BB * SS / 8, 256, 0, stream>>>(
      xyz, feat, nxyz, idx1, w1_0, b1_0, w1_1, b1_1, w1_2, b1_2, pf, 32);
  img_fuse_kernel<<<BB * SS / 32, 256, 0, stream>>>(
      imgf, pf, w_img, b_img, w_fc2, b_fc2, w_fc3, b_fc3, w_pc, b_pc,
      w_fuse, b_fuse, out);
}

// Round 7
// 4628.752 us; speedup vs baseline: 1.2730x; 1.2730x over previous
//
#include <hip/hip_runtime.h>
#include <cstdint>

typedef unsigned long long u64;

static constexpr int BB = 2;
static constexpr int NN = 16384;
static constexpr int SS = 4096;

// one step of a u64 max-combine via DPP (CTRL is a DPP control immediate)
template <int CTRL>
__device__ __forceinline__ u64 dpp_max_step(u64 k) {
  int lo = (int)(unsigned)(k & 0xffffffffull);
  int hi = (int)(unsigned)(k >> 32);
  int slo = __builtin_amdgcn_update_dpp(0, lo, CTRL, 0xF, 0xF, true);
  int shi = __builtin_amdgcn_update_dpp(0, hi, CTRL, 0xF, 0xF, true);
  u64 o = ((u64)(unsigned)shi << 32) | (u64)(unsigned)slo;
  return (o > k) ? o : k;
}

// spread 4 bits: bit k -> bit 3k (for 12-bit Morton)
__device__ __forceinline__ unsigned spread4(unsigned v) {
  return (v & 1u) | ((v & 2u) << 2) | ((v & 4u) << 4) | ((v & 8u) << 6);
}

__device__ __forceinline__ unsigned cell_of(float x, float y, float z) {
  int cx = (int)floorf((x + 4.f) * 2.f);
  int cy = (int)floorf((y + 4.f) * 2.f);
  int cz = (int)floorf((z + 4.f) * 2.f);
  cx = min(max(cx, 0), 15); cy = min(max(cy, 0), 15); cz = min(max(cz, 0), 15);
  return spread4((unsigned)cx) | (spread4((unsigned)cy) << 1) |
         (spread4((unsigned)cz) << 2);
}

// ---------------------------------------------------------------------------
// Counting sort by 12-bit Morton cell -> float4 {x,y,z,bits(orig_idx)}.
// Within-cell order is atomic-nondeterministic but the FPS output is
// invariant to it (keys carry original indices; skips are provable no-ops).
// ---------------------------------------------------------------------------
__global__ __launch_bounds__(1024) void sort_kernel(
    const float* __restrict__ xyz, float4* __restrict__ spts)
{
  const int b = blockIdx.x;
  const float* X = xyz + (size_t)b * NN * 3;
  float4* SP = spts + (size_t)b * NN;
  const int t = threadIdx.x;
  const int lane = t & 63, wid = t >> 6;

  __shared__ unsigned h[4096];
  __shared__ unsigned wtot[16];
  for (int j = t; j < 4096; j += 1024) h[j] = 0;
  __syncthreads();

  for (int i = 0; i < 16; ++i) {
    int p = i * 1024 + t;
    atomicAdd(&h[cell_of(X[p * 3 + 0], X[p * 3 + 1], X[p * 3 + 2])], 1u);
  }
  __syncthreads();

  unsigned a0 = h[4 * t], a1 = h[4 * t + 1], a2 = h[4 * t + 2], a3 = h[4 * t + 3];
  unsigned s4 = a0 + a1 + a2 + a3;
  unsigned incl = s4;
  for (int off = 1; off < 64; off <<= 1) {
    unsigned v = (unsigned)__shfl_up((int)incl, off);
    if (lane >= off) incl += v;
  }
  if (lane == 63) wtot[wid] = incl;
  __syncthreads();
  if (t == 0) {
    unsigned run = 0;
    for (int j = 0; j < 16; ++j) { unsigned tm = wtot[j]; wtot[j] = run; run += tm; }
  }
  __syncthreads();
  unsigned ex = wtot[wid] + (incl - s4);
  h[4 * t] = ex; h[4 * t + 1] = ex + a0;
  h[4 * t + 2] = ex + a0 + a1; h[4 * t + 3] = ex + a0 + a1 + a2;
  __syncthreads();

  for (int i = 0; i < 16; ++i) {
    int p = i * 1024 + t;
    float x = X[p * 3 + 0], y = X[p * 3 + 1], z = X[p * 3 + 2];
    unsigned pos = atomicAdd(&h[cell_of(x, y, z)], 1u);
    SP[pos] = make_float4(x, y, z, __int_as_float(p));
  }
}

// ---------------------------------------------------------------------------
// FPS, 256-pt-granularity exact pruning with REGISTER-resident coords.
// One block/batch, 16 waves; wave w owns sorted points [w*1024, w*1024+1024).
// Slot s of lane L = point w*1024 + s*64 + L, so slot-quad J (slots 4J..4J+3)
// is a CONTIGUOUS 256-point run with a tight bbox. All 16 slots' {x,y,z,~idx}
// plus running dists stay in named registers (R5 precedent: allocator backs
// this with the unified VGPR/AGPR file, zero memory traffic — R6's L2 reloads
// on the critical path were the regression).
// Per iteration: lane tests sub g=lane&3's bbox against that sub's cached
// exact max key; one ballot -> 4-bit active mask -> up to 4 wave-uniform
// register-only updates + per-sub DPP argmax. Skips are provably no-op fmin
// updates under both our and the reference's rounding (margin 1-2^-16).
// Keys (dist_bits<<32)|~orig_idx = numpy-exact argmax, first-index tie-break,
// invariant to sort nondeterminism.
// ---------------------------------------------------------------------------
__global__ __launch_bounds__(1024) void fps_kernel(
    const float* __restrict__ xyz, const float4* __restrict__ spts,
    float* __restrict__ new_xyz)
{
  const int b = blockIdx.x;
  const float* X = xyz + (size_t)b * NN * 3;
  float* NX = new_xyz + (size_t)b * SS * 3;
  const float4* SP = spts + (size_t)b * NN;
  const int t = threadIdx.x;
  const int lane = t & 63, wid = t >> 6;
  const int g = lane & 3;
  const float4* WP = SP + wid * 1024;

  float x0, x1, x2, x3, x4, x5, x6, x7, x8, x9, x10, x11, x12, x13, x14, x15;
  float y0, y1, y2, y3, y4, y5, y6, y7, y8, y9, y10, y11, y12, y13, y14, y15;
  float z0, z1, z2, z3, z4, z5, z6, z7, z8, z9, z10, z11, z12, z13, z14, z15;
  unsigned n0, n1, n2, n3, n4, n5, n6, n7, n8, n9, n10, n11, n12, n13, n14, n15;
#define LOADSLOT(s)                                                           \
  { float4 P = WP[(s) * 64 + lane];                                           \
    x##s = P.x; y##s = P.y; z##s = P.z; n##s = ~__float_as_uint(P.w); }
  LOADSLOT(0)  LOADSLOT(1)  LOADSLOT(2)  LOADSLOT(3)
  LOADSLOT(4)  LOADSLOT(5)  LOADSLOT(6)  LOADSLOT(7)
  LOADSLOT(8)  LOADSLOT(9)  LOADSLOT(10) LOADSLOT(11)
  LOADSLOT(12) LOADSLOT(13) LOADSLOT(14) LOADSLOT(15)
#undef LOADSLOT

  float d0 = 1e10f, d1 = 1e10f, d2 = 1e10f, d3 = 1e10f,
        d4 = 1e10f, d5 = 1e10f, d6 = 1e10f, d7 = 1e10f,
        d8 = 1e10f, d9 = 1e10f, d10 = 1e10f, d11 = 1e10f,
        d12 = 1e10f, d13 = 1e10f, d14 = 1e10f, d15 = 1e10f;

  // per-sub bbox; lane keeps the bbox of its group g (6 registers)
  float bnx = 0.f, bny = 0.f, bnz = 0.f, bxx = 0.f, bxy = 0.f, bxz = 0.f;
#define SUBBOX(J, A, B, C, D)                                                 \
  {                                                                           \
    float mnx = fminf(fminf(x##A, x##B), fminf(x##C, x##D));                  \
    float mxx = fmaxf(fmaxf(x##A, x##B), fmaxf(x##C, x##D));                  \
    float mny = fminf(fminf(y##A, y##B), fminf(y##C, y##D));                  \
    float mxy = fmaxf(fmaxf(y##A, y##B), fmaxf(y##C, y##D));                  \
    float mnz = fminf(fminf(z##A, z##B), fminf(z##C, z##D));                  \
    float mxz = fmaxf(fmaxf(z##A, z##B), fmaxf(z##C, z##D));                  \
    for (int off = 1; off < 64; off <<= 1) {                                  \
      mnx = fminf(mnx, __shfl_xor(mnx, off));                                 \
      mxx = fmaxf(mxx, __shfl_xor(mxx, off));                                 \
      mny = fminf(mny, __shfl_xor(mny, off));                                 \
      mxy = fmaxf(mxy, __shfl_xor(mxy, off));                                 \
      mnz = fminf(mnz, __shfl_xor(mnz, off));                                 \
      mxz = fmaxf(mxz, __shfl_xor(mxz, off));                                 \
    }                                                                         \
    if (g == J) { bnx = mnx; bny = mny; bnz = mnz;                            \
                  bxx = mxx; bxy = mxy; bxz = mxz; }                          \
  }
  SUBBOX(0, 0, 1, 2, 3)
  SUBBOX(1, 4, 5, 6, 7)
  SUBBOX(2, 8, 9, 10, 11)
  SUBBOX(3, 12, 13, 14, 15)
#undef SUBBOX

  // cached exact key of this lane's group; init forces all-active at iter 1
  unsigned klo = 0u, khi = __float_as_uint(1e10f);

  __shared__ u64 s_part[2][16];
  int sel = 0;

  for (int it = 1; it < SS; ++it) {
    const float qx = X[sel * 3 + 0];
    const float qy = X[sel * 3 + 1];
    const float qz = X[sel * 3 + 2];
    if (t == 0) {
      NX[(it - 1) * 3 + 0] = qx;
      NX[(it - 1) * 3 + 1] = qy;
      NX[(it - 1) * 3 + 2] = qz;
    }

    // conservative lower bound of dist^2(q, my group's bbox)
    float tx = fmaxf(fmaxf(__fsub_rn(bnx, qx), __fsub_rn(qx, bxx)), 0.f);
    float ty = fmaxf(fmaxf(__fsub_rn(bny, qy), __fsub_rn(qy, bxy)), 0.f);
    float tz = fmaxf(fmaxf(__fsub_rn(bnz, qz), __fsub_rn(qz, bxz)), 0.f);
    float lb2 = fmaf(tx, tx, fmaf(ty, ty, __fmul_rn(tz, tz)));
    u64 bm = __ballot(__fmul_rn(lb2, 0.99998474f) < __uint_as_float(khi));
    unsigned m = (unsigned)bm & 0xFu;  // lanes 0..3 = groups 0..3 (uniform)

#define UPD1(S)                                                               \
    {                                                                         \
      float dx = __fsub_rn(x##S, qx);                                         \
      float dy = __fsub_rn(y##S, qy);                                         \
      float dz = __fsub_rn(z##S, qz);                                         \
      float dsq = __fadd_rn(__fadd_rn(__fmul_rn(dx, dx), __fmul_rn(dy, dy)),  \
                            __fmul_rn(dz, dz));                               \
      d##S = fminf(d##S, dsq);                                                \
      u64 kp = ((u64)__float_as_uint(d##S) << 32) | (u64)(n##S);              \
      if (kp > kb) kb = kp;                                                   \
    }
#define SUBUPD(J, A, B, C, D)                                                 \
    if (m & (1u << J)) {                                                      \
      u64 kb = 0;                                                             \
      UPD1(A) UPD1(B) UPD1(C) UPD1(D)                                         \
      kb = dpp_max_step<0x111>(kb);                                           \
      kb = dpp_max_step<0x112>(kb);                                           \
      kb = dpp_max_step<0x114>(kb);                                           \
      kb = dpp_max_step<0x118>(kb);                                           \
      kb = dpp_max_step<0x142>(kb);                                           \
      kb = dpp_max_step<0x143>(kb);                                           \
      unsigned nlo = (unsigned)__shfl((int)(unsigned)(kb & 0xffffffffull), 63);\
      unsigned nhi = (unsigned)__shfl((int)(unsigned)(kb >> 32), 63);         \
      if (g == J) { klo = nlo; khi = nhi; }                                   \
    }
    SUBUPD(0, 0, 1, 2, 3)
    SUBUPD(1, 4, 5, 6, 7)
    SUBUPD(2, 8, 9, 10, 11)
    SUBUPD(3, 12, 13, 14, 15)
#undef SUBUPD
#undef UPD1

    // wave key = max over the 4 group keys (lane-distributed in quads)
    u64 kw = ((u64)khi << 32) | (u64)klo;
    kw = dpp_max_step<0xB1>(kw);  // quad_perm [1,0,3,2]
    kw = dpp_max_step<0x4E>(kw);  // quad_perm [2,3,0,1]

    const int pb = it & 1;
    if (lane == 63) s_part[pb][wid] = kw;
    __syncthreads();
    u64 kk = s_part[pb][lane & 15];
    kk = dpp_max_step<0x128>(kk);  // row_ror:8
    kk = dpp_max_step<0x124>(kk);  // row_ror:4
    kk = dpp_max_step<0x122>(kk);  // row_ror:2
    kk = dpp_max_step<0x121>(kk);  // row_ror:1
    sel = (int)(~(unsigned)(kk & 0xffffffffull));
    sel = __builtin_amdgcn_readfirstlane(sel);
  }
  if (t == 0) {
    NX[(SS - 1) * 3 + 0] = X[sel * 3 + 0];
    NX[(SS - 1) * 3 + 1] = X[sel * 3 + 1];
    NX[(SS - 1) * 3 + 2] = X[sel * 3 + 2];
  }
}

// ---------------------------------------------------------------------------
// Ball query: one 64-lane wave per query point. Emits the first NS in-radius
// point indices in ascending order (matches reference top_k(-keys) trick),
// pads with the first hit.
// ---------------------------------------------------------------------------
template <int NS>
__global__ __launch_bounds__(256) void ballq_kernel(
    const float* __restrict__ xyz, const float* __restrict__ new_xyz,
    int* __restrict__ out, float r2)
{
  const int q = blockIdx.x * 4 + (threadIdx.x >> 6);
  const int lane = threadIdx.x & 63;
  const int b = q >> 12;  // q / SS
  const float* X = xyz + (size_t)b * NN * 3;
  const float cx = new_xyz[q * 3 + 0];
  const float cy = new_xyz[q * 3 + 1];
  const float cz = new_xyz[q * 3 + 2];
  int* o = out + (size_t)q * NS;
  int base = 0;
  int firstIdx = 0x7fffffff;
  for (int c0 = 0; c0 < NN; c0 += 64) {
    const int p = c0 + lane;
    float dx = __fsub_rn(cx, X[p * 3 + 0]);
    float dy = __fsub_rn(cy, X[p * 3 + 1]);
    float dz = __fsub_rn(cz, X[p * 3 + 2]);
    float d2 = __fadd_rn(__fadd_rn(__fmul_rn(dx, dx), __fmul_rn(dy, dy)),
                         __fmul_rn(dz, dz));
    const bool inb = d2 < r2;
    const unsigned long long mm = __ballot(inb);
    if (inb) {
      int rank = base + (int)__popcll(mm & ((1ull << lane) - 1ull));
      if (rank < NS) {
        o[rank] = p;
        if (rank == 0) firstIdx = p;
      }
    }
    base += (int)__popcll(mm);
    if (base >= NS) break;
  }
#pragma unroll
  for (int off = 32; off >= 1; off >>= 1)
    firstIdx = min(firstIdx, __shfl_xor(firstIdx, off));
  for (int r = base + lane; r < NS; r += 64) o[r] = firstIdx;
}

// ---------------------------------------------------------------------------
// Grouping + 3-layer MLP + max over samples. One thread per (query, sample).
// ---------------------------------------------------------------------------
template <int NS, int C1, int C2, int C3>
__global__ __launch_bounds__(256) void group_mlp_kernel(
    const float* __restrict__ xyz, const float* __restrict__ feat,
    const float* __restrict__ new_xyz, const int* __restrict__ idx,
    const float* __restrict__ w0, const float* __restrict__ b0,
    const float* __restrict__ w1, const float* __restrict__ b1,
    const float* __restrict__ w2, const float* __restrict__ b2,
    float* __restrict__ pf, int chOff)
{
  constexpr int QPB = 256 / NS;
  const int q = blockIdx.x * QPB + (int)(threadIdx.x / NS);
  const int k = (int)(threadIdx.x % NS);
  const int b = q >> 12;
  const int s = q & (SS - 1);
  const float* X = xyz + (size_t)b * NN * 3;
  const float* F = feat + (size_t)b * 6 * NN;
  const int p = idx[(size_t)q * NS + k];

  float in[9];
  in[0] = X[p * 3 + 0] - new_xyz[q * 3 + 0];
  in[1] = X[p * 3 + 1] - new_xyz[q * 3 + 1];
  in[2] = X[p * 3 + 2] - new_xyz[q * 3 + 2];
#pragma unroll
  for (int c = 0; c < 6; ++c) in[3 + c] = F[c * NN + p];

  float h1[C1];
#pragma unroll
  for (int oc = 0; oc < C1; ++oc) {
    float a = b0[oc];
#pragma unroll
    for (int c = 0; c < 9; ++c) a = fmaf(w0[oc * 9 + c], in[c], a);
    h1[oc] = fmaxf(a, 0.f);
  }
  float h2[C2];
#pragma unroll
  for (int oc = 0; oc < C2; ++oc) {
    float a = b1[oc];
#pragma unroll
    for (int c = 0; c < C1; ++c) a = fmaf(w1[oc * C1 + c], h1[c], a);
    h2[oc] = fmaxf(a, 0.f);
  }
#pragma unroll
  for (int oc = 0; oc < C3; ++oc) {
    float a = b2[oc];
#pragma unroll
    for (int c = 0; c < C2; ++c) a = fmaf(w2[oc * C2 + c], h2[c], a);
    float v = fmaxf(a, 0.f);
#pragma unroll
    for (int off = NS / 2; off >= 1; off >>= 1)
      v = fmaxf(v, __shfl_xor(v, off));
    if (k == 0) pf[(((size_t)b * 96) + chOff + oc) * SS + s] = v;
  }
}

// ---------------------------------------------------------------------------
// Image branch + attention + fusion, 32-column LDS tiles.
// ---------------------------------------------------------------------------
__global__ __launch_bounds__(256) void img_fuse_kernel(
    const float* __restrict__ imgf, const float* __restrict__ pf,
    const float* __restrict__ w_img, const float* __restrict__ b_img,
    const float* __restrict__ w_fc2, const float* __restrict__ b_fc2,
    const float* __restrict__ w_fc3, const float* __restrict__ b_fc3,
    const float* __restrict__ w_pc, const float* __restrict__ b_pc,
    const float* __restrict__ w_fuse, const float* __restrict__ b_fuse,
    float* __restrict__ out)
{
  constexpr int TS = 32;
  __shared__ float x_lds[64][TS];
  __shared__ float img_lds[96][TS];
  __shared__ float ri_lds[24][TS];
  __shared__ float att_lds[TS];
  __shared__ float imgn_lds[96][TS];
  __shared__ float pf_lds[96][TS];

  const int blk = blockIdx.x;            // B * (SS/TS) = 256 blocks
  const int b = blk / (SS / TS);
  const int s0 = (blk % (SS / TS)) * TS;
  const int tid = threadIdx.x;

  for (int i = tid; i < 64 * TS; i += 256) {
    int c = i / TS, s = i % TS;
    x_lds[c][s] = imgf[((size_t)b * 64 + c) * SS + s0 + s];
  }
  for (int i = tid; i < 96 * TS; i += 256) {
    int c = i / TS, s = i % TS;
    pf_lds[c][s] = pf[((size_t)b * 96 + c) * SS + s0 + s];
  }
  __syncthreads();

  for (int i = tid; i < 96 * TS; i += 256) {
    int oc = i / TS, s = i % TS;
    float a = b_img[oc];
#pragma unroll
    for (int c = 0; c < 64; ++c) a = fmaf(w_img[oc * 64 + c], x_lds[c][s], a);
    img_lds[oc][s] = fmaxf(a, 0.f);
  }
  __syncthreads();

  for (int i = tid; i < 24 * TS; i += 256) {
    int r = i / TS, s = i % TS;
    float a = b_fc2[r];
#pragma unroll
    for (int c = 0; c < 96; ++c) a = fmaf(w_fc2[r * 96 + c], img_lds[c][s], a);
    ri_lds[r][s] = tanhf(a);
  }
  __syncthreads();

  if (tid < TS) {
    float a = b_fc3[0];
#pragma unroll
    for (int r = 0; r < 24; ++r) a = fmaf(w_fc3[r], ri_lds[r][tid], a);
    att_lds[tid] = 1.f / (1.f + expf(-a));
  }
  __syncthreads();

  for (int i = tid; i < 96 * TS; i += 256) {
    int c = i / TS, s = i % TS;
    float v = img_lds[c][s];
    img_lds[c][s] = fmaf(v, att_lds[s], v);
  }
  __syncthreads();

  for (int i = tid; i < 96 * TS; i += 256) {
    int oc = i / TS, s = i % TS;
    float a = b_pc[oc];
#pragma unroll
    for (int c = 0; c < 96; ++c) a = fmaf(w_pc[oc * 96 + c], img_lds[c][s], a);
    imgn_lds[oc][s] = fmaxf(a, 0.f);
  }
  __syncthreads();

  for (int i = tid; i < 128 * TS; i += 256) {
    int oc = i / TS, s = i % TS;
    float a = b_fuse[oc];
#pragma unroll
    for (int c = 0; c < 96; ++c) a = fmaf(w_fuse[oc * 192 + c], pf_lds[c][s], a);
#pragma unroll
    for (int c = 0; c < 96; ++c) a = fmaf(w_fuse[oc * 192 + 96 + c], imgn_lds[c][s], a);
    out[((size_t)b * 128 + oc) * SS + s0 + s] = fmaxf(a, 0.f);
  }
}

// ---------------------------------------------------------------------------
extern "C" void kernel_launch(void* const* d_in, const int* in_sizes, int n_in,
                              void* d_out, int out_size, void* d_ws, size_t ws_size,
                              hipStream_t stream)
{
  const float* xyz    = (const float*)d_in[0];
  const float* feat   = (const float*)d_in[1];
  const float* imgf   = (const float*)d_in[2];
  const float* w0_0   = (const float*)d_in[3];
  const float* b0_0   = (const float*)d_in[4];
  const float* w0_1   = (const float*)d_in[5];
  const float* b0_1   = (const float*)d_in[6];
  const float* w0_2   = (const float*)d_in[7];
  const float* b0_2   = (const float*)d_in[8];
  const float* w1_0   = (const float*)d_in[9];
  const float* b1_0   = (const float*)d_in[10];
  const float* w1_1   = (const float*)d_in[11];
  const float* b1_1   = (const float*)d_in[12];
  const float* w1_2   = (const float*)d_in[13];
  const float* b1_2   = (const float*)d_in[14];
  const float* w_img  = (const float*)d_in[15];
  const float* b_img  = (const float*)d_in[16];
  const float* w_fc2  = (const float*)d_in[17];
  const float* b_fc2  = (const float*)d_in[18];
  const float* w_fc3  = (const float*)d_in[19];
  const float* b_fc3  = (const float*)d_in[20];
  const float* w_pc   = (const float*)d_in[21];
  const float* b_pc   = (const float*)d_in[22];
  const float* w_fuse = (const float*)d_in[23];
  const float* b_fuse = (const float*)d_in[24];
  float* out = (float*)d_out;

  float4* spts = (float4*)d_ws;                          // B*N float4
  float*  nxyz = (float*)(spts + (size_t)BB * NN);       // B*S*3 f32
  int*    idx0 = (int*)(nxyz + (size_t)BB * SS * 3);     // B*S*16 i32
  int*    idx1 = idx0 + (size_t)BB * SS * 16;            // B*S*32 i32
  float*  pf   = (float*)(idx1 + (size_t)BB * SS * 32);  // B*96*S f32

  sort_kernel<<<BB, 1024, 0, stream>>>(xyz, spts);
  fps_kernel<<<BB, 1024, 0, stream>>>(xyz, spts, nxyz);
  ballq_kernel<16><<<BB * SS / 4, 256, 0, stream>>>(xyz, nxyz, idx0, 0.25f);
  ballq_kernel<32><<<BB * SS / 4, 256, 0, stream>>>(xyz, nxyz, idx1, 1.0f);
  group_mlp_kernel<16, 16, 16, 32><<<BB * SS / 16, 256, 0, stream>>>(
      xyz, feat, nxyz, idx0, w0_0, b0_0, w0_1, b0_1, w0_2, b0_2, pf, 0);
  group_mlp_kernel<32, 32, 32, 64><<<BB * SS / 8, 256, 0, stream>>>(
      xyz, feat, nxyz, idx1, w1_0, b1_0, w1_1, b1_1, w1_2, b1_2, pf, 32);
  img_fuse_kernel<<<BB * SS / 32, 256, 0, stream>>>(
      imgf, pf, w_img, b_img, w_fc2, b_fc2, w_fc3, b_fc3, w_pc, b_pc,
      w_fuse, b_fuse, out);
}